// Round 8
// baseline (744.263 us; speedup 1.0000x reference)
//
#include <hip/hip_runtime.h>
#include <hip/hip_cooperative_groups.h>

namespace cg = cooperative_groups;

#define NVOX 200000
#define TM 128
#define NBLK 1563   // ceil(200000/128)
#define NREP 32     // stats-accumulator replicas
#define STG 4224    // floats per stage: 32*128 replicas + 64 scale + 64 shift

typedef unsigned short u16;
typedef unsigned int u32;
typedef __bf16 bf16x8 __attribute__((ext_vector_type(8)));
typedef float f32x16 __attribute__((ext_vector_type(16)));

__device__ __forceinline__ float bf2f(u16 h) { return __uint_as_float(((u32)h) << 16); }
__device__ __forceinline__ u16 f2bf(float x) {
  u32 u = __float_as_uint(x);
  u32 r = u + 0x7fffu + ((u >> 16) & 1u);   // RNE
  return (u16)(r >> 16);
}
__device__ __forceinline__ uint4 cvt8(uint4 a, uint4 b) {
  const float* fa = (const float*)&a;
  const float* fb = (const float*)&b;
  uint4 r;
  u16* q = (u16*)&r;
#pragma unroll
  for (int j = 0; j < 4; ++j) { q[j] = f2bf(fa[j]); q[4 + j] = f2bf(fb[j]); }
  return r;
}

__device__ __forceinline__ void bn_from_replicas(const float* stp, const float* g,
                                                 const float* b, int c,
                                                 float* sc, float* sh) {
  float s = 0.f, q = 0.f;
#pragma unroll
  for (int r = 0; r < NREP; ++r) {
    s += stp[r * 128 + c];
    q += stp[r * 128 + 64 + c];
  }
  const float invn = 1.0f / (float)NVOX;
  float mean = s * invn;
  float var = q * invn - mean * mean;
  float sca = g[c] * rsqrtf(var + 1e-5f);
  *sc = sca;
  *sh = b[c] - mean * sca;
}

// ---------------------------------------------------------------------------
// Round 14: single persistent cooperative kernel for the fused tier.
// Phases (grid.sync between): prep -> convA -> wscale -> convB -> final.
// Conv bodies are round-6's verbatim (best measured, 65 us/dispatch); the
// change this round is structural: 5 dispatches -> 1, killing 4 launch gaps
// and 4 grid drain/fill ramps (~90 us of e2e not attributable to passes).
// Grid size from runtime occupancy query (all phases grid-stride -> safe).
// ---------------------------------------------------------------------------
struct MegaParams {
  const float* feat;
  const float* w1; const float* w1_2; const float* w2; const float* w3;
  const float* g0; const float* b0; const float* g0_2; const float* b0_2;
  const float* g1; const float* b1; const float* g2; const float* b2;
  const int* nbr13; const int* nbr31;
  float* out;
  float* stats; float* st0; float* st1; float* st2; float* st3;
  u16* wf; u16* s0; u16* s1; u16* s2; u16* s3;
  u16* F; u16* A1; u16* A2;
};

// prep: cvt feat->F bf16 (bids [0,6250)), raw frags (bids [6250,6538)), stats zero
__device__ void prep_body(int bid, const MegaParams& p) {
  const int tid = threadIdx.x;
  if (bid < 6250) {
    int i8 = (bid * 256 + tid) * 8;
    if (i8 < NVOX * 64) {
      uint4 a = *(const uint4*)(p.feat + i8);
      uint4 b = *(const uint4*)(p.feat + i8 + 4);
      *(uint4*)(p.F + i8) = cvt8(a, b);
    }
    return;
  }
  int rb = bid - 6250;
  if (rb < 288) {   // raw frags: [slot 0|1][k][ks*2+ct][lane][j]
    int e = rb * 256 + tid;
    int slot = e / 36864, r = e % 36864;
    int k = r >> 12, rr = r & 4095;
    int frag = rr >> 9, lane = (rr >> 3) & 63, j = rr & 7;
    int ks = frag >> 1, ct = frag & 1;
    int cin = ks * 16 + (lane >> 5) * 8 + j;
    int cout = ct * 32 + (lane & 31);
    const float* src = slot ? p.w2 : p.w1;
    p.wf[e] = f2bf(src[k * 4096 + cin * 64 + cout]);
    return;
  }
  for (int i = tid; i < 4 * STG; i += 256) p.stats[i] = 0.f;
}

// conv body == round-6 conv_fused, as a device function over virtual bid.
template <int PHASE>
__device__ void conv_body(int bid, const u16* inA, const u16* inB,
                          const int* nbrA, const int* nbrB,
                          const u16* wfA, const u16* wfB,
                          void* yA, void* yB, float* stA, float* stB,
                          float* fb4, float (*sred)[128]) {
  const int tid = threadIdx.x;
  const bool hB = (bid >= NBLK);
  const int blk = hB ? bid - NBLK : bid;
  const u16* f = hB ? inB : inA;
  const int* nbr = hB ? nbrB : nbrA;
  const u16* wf = hB ? wfB : wfA;
  float* st = hB ? stB : stA;

  const int wv = tid >> 6;
  const int lane = tid & 63;
  const int lrow = lane & 31;
  const int lq = lane >> 5;
  const int base = blk * TM;
  const int gr = base + wv * 32 + lrow;

  int ids[9];
#pragma unroll
  for (int j = 0; j < 9; ++j) ids[j] = (gr < NVOX) ? nbr[gr * 9 + j] : NVOX;

  f32x16 acc0 = {0.f, 0.f, 0.f, 0.f, 0.f, 0.f, 0.f, 0.f,
                 0.f, 0.f, 0.f, 0.f, 0.f, 0.f, 0.f, 0.f};
  f32x16 acc1 = acc0;
  constexpr bool FOLDED = (PHASE == 1);
  constexpr int KSTRIDE = FOLDED ? 5120 : 4096;

#pragma unroll
  for (int k = 0; k < 9; ++k) {
    if (k != 4) {
      if (__ballot(ids[k] < NVOX) == 0ull) continue;
    }
    const int id = ids[k];
    const bool ok = id < NVOX;
    uint4 af[4];
    const u16* pp = f + (size_t)id * 64 + lq * 8;
#pragma unroll
    for (int ksi = 0; ksi < 4; ++ksi) {
      uint4 v = make_uint4(0u, 0u, 0u, 0u);
      if (ok) v = *(const uint4*)(pp + ksi * 16);
      af[ksi] = v;
    }
    const u16* wb = wf + k * KSTRIDE;
#pragma unroll
    for (int ksi = 0; ksi < 4; ++ksi) {
      bf16x8 a = __builtin_bit_cast(bf16x8, af[ksi]);
      bf16x8 b0 = __builtin_bit_cast(bf16x8, *(const uint4*)(wb + (ksi * 2) * 512 + lane * 8));
      bf16x8 b1 = __builtin_bit_cast(bf16x8, *(const uint4*)(wb + (ksi * 2 + 1) * 512 + lane * 8));
      acc0 = __builtin_amdgcn_mfma_f32_32x32x16_bf16(a, b0, acc0, 0, 0, 0);
      acc1 = __builtin_amdgcn_mfma_f32_32x32x16_bf16(a, b1, acc1, 0, 0, 0);
    }
    if constexpr (FOLDED) {   // bias channel: A = 1[exists] at (lq=0, j=0)
      uint4 a4 = make_uint4(0u, 0u, 0u, 0u);
      if (lq == 0 && ok) ((u16*)&a4)[0] = 0x3F80u;
      bf16x8 a = __builtin_bit_cast(bf16x8, a4);
      bf16x8 b0 = __builtin_bit_cast(bf16x8, *(const uint4*)(wb + 8 * 512 + lane * 8));
      bf16x8 b1 = __builtin_bit_cast(bf16x8, *(const uint4*)(wb + 9 * 512 + lane * 8));
      acc0 = __builtin_amdgcn_mfma_f32_32x32x16_bf16(a, b0, acc0, 0, 0, 0);
      acc1 = __builtin_amdgcn_mfma_f32_32x32x16_bf16(a, b1, acc1, 0, 0, 0);
    }
  }

  // Epilogue. C/D (32x32): col = lane&31, row = (reg&3) + 8*(reg>>2) + 4*(lane>>5)
  const int cc0 = lrow, cc1 = 32 + lrow;
  float s0 = 0.f, q0 = 0.f, s1 = 0.f, q1 = 0.f;
  float vout[2][16];
#pragma unroll
  for (int r = 0; r < 16; ++r) {
    float v = acc0[r]; v = v > 0.f ? v : 0.01f * v;
    s0 += v; q0 += v * v; vout[0][r] = v;
    float w = acc1[r]; w = w > 0.f ? w : 0.01f * w;
    s1 += w; q1 += w * w; vout[1][r] = w;
  }
  s0 += __shfl_xor(s0, 32); q0 += __shfl_xor(q0, 32);
  s1 += __shfl_xor(s1, 32); q1 += __shfl_xor(q1, 32);
  if (lq == 0) {   // rows >= NVOX contribute exact 0
    sred[wv][lrow] = s0; sred[wv][32 + lrow] = s1;
    sred[wv][64 + lrow] = q0; sred[wv][96 + lrow] = q1;
  }

  const bool f32out = (PHASE == 1) && !hB;
  const int trow = tid >> 3, cp = tid & 7;
  u16* bb = (u16*)fb4;
#pragma unroll
  for (int h = 0; h < 2; ++h) {
    __syncthreads();
    if ((wv >> 1) == h) {
      const int lr = 32 * (wv & 1);
#pragma unroll
      for (int r = 0; r < 16; ++r) {
        int rowD = lr + (r & 3) + 8 * (r >> 2) + 4 * lq;
        if (f32out) {
          fb4[rowD * 68 + cc0] = vout[0][r];
          fb4[rowD * 68 + cc1] = vout[1][r];
        } else {
          bb[rowD * 72 + cc0] = f2bf(vout[0][r]);
          bb[rowD * 72 + cc1] = f2bf(vout[1][r]);
        }
      }
    }
    __syncthreads();
    if (f32out) {
      float* y = (float*)yA;
#pragma unroll
      for (int it = 0; it < 2; ++it) {
        int r = it * 32 + trow, row = base + 64 * h + r;
        if (row < NVOX) {
          *(float4*)(y + (size_t)row * 64 + cp * 8) = *(const float4*)(fb4 + r * 68 + cp * 8);
          *(float4*)(y + (size_t)row * 64 + cp * 8 + 4) = *(const float4*)(fb4 + r * 68 + cp * 8 + 4);
        }
      }
    } else {
      u16* y = (u16*)(hB ? yB : yA);
#pragma unroll
      for (int it = 0; it < 2; ++it) {
        int r = it * 32 + trow, row = base + 64 * h + r;
        if (row < NVOX)
          *(uint4*)(y + (size_t)row * 64 + cp * 8) = *(const uint4*)(bb + r * 72 + cp * 8);
      }
    }
  }
  if (tid < 128) {
    int which = tid >> 6, c = tid & 63;
    float v = sred[0][which * 64 + c] + sred[1][which * 64 + c] +
              sred[2][which * 64 + c] + sred[3][which * 64 + c];
    atomicAdd(&st[(bid & (NREP - 1)) * 128 + which * 64 + c], v);
  }
  __syncthreads();   // protect sred/fb4 reuse across grid-stride iterations
}

// wscale: fold BN into second-conv weights (virtual bids [0,360))
__device__ void wscale_body(int blkid, const MegaParams& p, float* smem) {
  float* sc = smem;
  float* sh = smem + 64;
  const int tid = threadIdx.x;
  const bool hB = (blkid >= 180);
  const float* wraw = hB ? p.w3 : p.w1_2;
  float* stp = hB ? p.st2 : p.st0;
  const float* g = hB ? p.g1 : p.g0;
  const float* b = hB ? p.b1 : p.b0;
  u16* dst = hB ? p.s3 : p.s2;
  const int blk = hB ? blkid - 180 : blkid;
  if (tid < 64) {
    float a, h;
    bn_from_replicas(stp, g, b, tid, &a, &h);
    sc[tid] = a; sh[tid] = h;
  }
  __syncthreads();
  int e = blk * 256 + tid;   // [0, 46080)
  int k = e / 5120, r = e % 5120;
  int frag = r >> 9, lane = (r >> 3) & 63, j = r & 7;
  int ks = frag >> 1, ct = frag & 1;
  int cout = ct * 32 + (lane & 31);
  u16 val = 0;
  if (ks < 4) {
    int cin = ks * 16 + (lane >> 5) * 8 + j;
    val = f2bf(sc[cin] * wraw[k * 4096 + cin * 64 + cout]);
  } else if (((lane >> 5) == 0) && j == 0) {
    float acc = 0.f;
    for (int c = 0; c < 64; ++c) acc += sh[c] * wraw[k * 4096 + c * 64 + cout];
    val = f2bf(acc);
  }
  dst[e] = val;
  __syncthreads();   // protect sc/sh reuse across grid-stride iterations
}

// final: out = affB(out) + affD(F bf16); affines computed once per block
__device__ void final_body(const MegaParams& p, float* smem, int nb) {
  float* aff = smem;   // [4][64]
  const int t = threadIdx.x;
  if (t < 128) {
    float a, h;
    if (t < 64) {
      bn_from_replicas(p.st1, p.g0_2, p.b0_2, t, &a, &h);
      aff[t] = a; aff[64 + t] = h;
    } else {
      int c = t - 64;
      bn_from_replicas(p.st3, p.g2, p.b2, c, &a, &h);
      aff[128 + c] = a; aff[192 + c] = h;
    }
  }
  __syncthreads();
  for (int b = blockIdx.x; b < 6250; b += nb) {
    int i8 = (b * 256 + t) * 8;
    if (i8 < NVOX * 64) {
      float a[8];
      *(float4*)&a[0] = *(const float4*)(p.out + i8);
      *(float4*)&a[4] = *(const float4*)(p.out + i8 + 4);
      uint4 vd = *(const uint4*)(p.F + i8);
      const u16* pd = (const u16*)&vd;
      int cb = i8 & 63;
      float o[8];
#pragma unroll
      for (int j = 0; j < 8; ++j) {
        int c = cb + j;
        o[j] = fmaf(a[j], aff[c], aff[64 + c]) + fmaf(bf2f(pd[j]), aff[128 + c], aff[192 + c]);
      }
      *(float4*)(p.out + i8) = *(const float4*)&o[0];
      *(float4*)(p.out + i8 + 4) = *(const float4*)&o[4];
    }
  }
}

__global__ __launch_bounds__(256, 6) void mega(MegaParams p) {
  __shared__ __align__(16) float fb4[64 * 68];   // 17,408 B
  __shared__ float sred[4][128];                 //  2,048 B
  cg::grid_group grid = cg::this_grid();
  const int nb = gridDim.x;

  for (int b = blockIdx.x; b < 6539; b += nb) prep_body(b, p);
  grid.sync();
  for (int b = blockIdx.x; b < 2 * NBLK; b += nb)
    conv_body<0>(b, p.F, p.F, p.nbr13, p.nbr31, p.s0, p.s1,
                 p.A1, p.A2, p.st0, p.st2, fb4, sred);
  grid.sync();
  for (int b = blockIdx.x; b < 360; b += nb) wscale_body(b, p, fb4);
  grid.sync();
  for (int b = blockIdx.x; b < 2 * NBLK; b += nb)
    conv_body<1>(b, p.A1, p.A2, p.nbr31, p.nbr13, p.s2, p.s3,
                 p.out, p.F, p.st1, p.st3, fb4, sred);
  grid.sync();
  final_body(p, fb4, nb);
}

// ---- round-6 serial conv (fallback tiers) ---------------------------------
template <bool IN_F32, bool FOLDED, int MODE>
__global__ __launch_bounds__(256, 4)
void conv_k(const void* __restrict__ fv, const int* __restrict__ nbr,
            const u16* __restrict__ wf, void* yv, float* __restrict__ st,
            float* io, const float* __restrict__ affD,
            const float* __restrict__ affB) {
  __shared__ __align__(16) float fb[128 * 68];
  __shared__ float sred[4][128];

  const int tid = threadIdx.x;
  const int wv = tid >> 6;
  const int lane = tid & 63;
  const int lrow = lane & 31;
  const int lq = lane >> 5;
  const int base = blockIdx.x * TM;
  const int gr = base + wv * 32 + lrow;

  int ids[9];
#pragma unroll
  for (int j = 0; j < 9; ++j) ids[j] = (gr < NVOX) ? nbr[gr * 9 + j] : NVOX;

  f32x16 acc0 = {0.f, 0.f, 0.f, 0.f, 0.f, 0.f, 0.f, 0.f,
                 0.f, 0.f, 0.f, 0.f, 0.f, 0.f, 0.f, 0.f};
  f32x16 acc1 = acc0;
  constexpr int KSTRIDE = FOLDED ? 5120 : 4096;

#pragma unroll
  for (int k = 0; k < 9; ++k) {
    if (k != 4) {
      if (__ballot(ids[k] < NVOX) == 0ull) continue;
    }
    const int id = ids[k];
    const bool ok = id < NVOX;
    uint4 af[4];
    if constexpr (IN_F32) {
      const float* p = (const float*)fv + (size_t)id * 64 + lq * 8;
#pragma unroll
      for (int ksi = 0; ksi < 4; ++ksi) {
        uint4 v0 = make_uint4(0u, 0u, 0u, 0u), v1 = v0;
        if (ok) { v0 = *(const uint4*)(p + ksi * 16); v1 = *(const uint4*)(p + ksi * 16 + 4); }
        af[ksi] = cvt8(v0, v1);
      }
    } else {
      const u16* p = (const u16*)fv + (size_t)id * 64 + lq * 8;
#pragma unroll
      for (int ksi = 0; ksi < 4; ++ksi) {
        uint4 v = make_uint4(0u, 0u, 0u, 0u);
        if (ok) v = *(const uint4*)(p + ksi * 16);
        af[ksi] = v;
      }
    }
    const u16* wb = wf + k * KSTRIDE;
#pragma unroll
    for (int ksi = 0; ksi < 4; ++ksi) {
      bf16x8 a = __builtin_bit_cast(bf16x8, af[ksi]);
      bf16x8 b0 = __builtin_bit_cast(bf16x8, *(const uint4*)(wb + (ksi * 2) * 512 + lane * 8));
      bf16x8 b1 = __builtin_bit_cast(bf16x8, *(const uint4*)(wb + (ksi * 2 + 1) * 512 + lane * 8));
      acc0 = __builtin_amdgcn_mfma_f32_32x32x16_bf16(a, b0, acc0, 0, 0, 0);
      acc1 = __builtin_amdgcn_mfma_f32_32x32x16_bf16(a, b1, acc1, 0, 0, 0);
    }
    if constexpr (FOLDED) {
      uint4 a4 = make_uint4(0u, 0u, 0u, 0u);
      if (lq == 0 && ok) ((u16*)&a4)[0] = 0x3F80u;
      bf16x8 a = __builtin_bit_cast(bf16x8, a4);
      bf16x8 b0 = __builtin_bit_cast(bf16x8, *(const uint4*)(wb + 8 * 512 + lane * 8));
      bf16x8 b1 = __builtin_bit_cast(bf16x8, *(const uint4*)(wb + 9 * 512 + lane * 8));
      acc0 = __builtin_amdgcn_mfma_f32_32x32x16_bf16(a, b0, acc0, 0, 0, 0);
      acc1 = __builtin_amdgcn_mfma_f32_32x32x16_bf16(a, b1, acc1, 0, 0, 0);
    }
  }

  const int cc0 = lrow, cc1 = 32 + lrow;
  float aD0 = 0.f, aD1 = 0.f, hD0 = 0.f, hD1 = 0.f;
  if constexpr (MODE == 2) {
    aD0 = affD[cc0]; hD0 = affD[64 + cc0];
    aD1 = affD[cc1]; hD1 = affD[64 + cc1];
  }
  float s0 = 0.f, q0 = 0.f, s1 = 0.f, q1 = 0.f;
  float vout[2][16];
#pragma unroll
  for (int r = 0; r < 16; ++r) {
    float v = acc0[r]; v = v > 0.f ? v : 0.01f * v;
    s0 += v; q0 += v * v; vout[0][r] = v;
    float w = acc1[r]; w = w > 0.f ? w : 0.01f * w;
    s1 += w; q1 += w * w; vout[1][r] = w;
  }
  if constexpr (MODE != 2) {
    s0 += __shfl_xor(s0, 32); q0 += __shfl_xor(q0, 32);
    s1 += __shfl_xor(s1, 32); q1 += __shfl_xor(q1, 32);
    if (lq == 0) {
      sred[wv][lrow] = s0; sred[wv][32 + lrow] = s1;
      sred[wv][64 + lrow] = q0; sred[wv][96 + lrow] = q1;
    }
  }
  if constexpr (MODE == 0) {
    u16* bb = (u16*)fb;
#pragma unroll
    for (int r = 0; r < 16; ++r) {
      int rowD = 32 * wv + (r & 3) + 8 * (r >> 2) + 4 * lq;
      bb[rowD * 72 + cc0] = f2bf(vout[0][r]);
      bb[rowD * 72 + cc1] = f2bf(vout[1][r]);
    }
  } else if constexpr (MODE == 2 || MODE == 3) {
#pragma unroll
    for (int r = 0; r < 16; ++r) {
      int rowD = 32 * wv + (r & 3) + 8 * (r >> 2) + 4 * lq;
      float v0 = vout[0][r], v1 = vout[1][r];
      if constexpr (MODE == 2) { v0 = fmaf(v0, aD0, hD0); v1 = fmaf(v1, aD1, hD1); }
      fb[rowD * 68 + cc0] = v0;
      fb[rowD * 68 + cc1] = v1;
    }
  }
  __syncthreads();

  const int trow = tid >> 3, cp = tid & 7;
  if constexpr (MODE == 0) {
    u16* y = (u16*)yv;
    const u16* bb = (const u16*)fb;
#pragma unroll
    for (int it = 0; it < 4; ++it) {
      int r = it * 32 + trow, row = base + r;
      if (row < NVOX)
        *(uint4*)(y + (size_t)row * 64 + cp * 8) = *(const uint4*)(bb + r * 72 + cp * 8);
    }
  }
  if constexpr (MODE == 3) {
    float* y = (float*)yv;
#pragma unroll
    for (int it = 0; it < 4; ++it) {
      int r = it * 32 + trow, row = base + r;
      if (row < NVOX) {
        *(float4*)(y + (size_t)row * 64 + cp * 8) = *(const float4*)(fb + r * 68 + cp * 8);
        *(float4*)(y + (size_t)row * 64 + cp * 8 + 4) = *(const float4*)(fb + r * 68 + cp * 8 + 4);
      }
    }
  }
  if constexpr (MODE == 2) {
    float* y = (float*)yv;
#pragma unroll
    for (int it = 0; it < 4; ++it) {
      int r = it * 32 + trow, row = base + r;
      if (row < NVOX) {
        float t[8], pp[8], o[8];
        *(float4*)&t[0] = *(const float4*)(fb + r * 68 + cp * 8);
        *(float4*)&t[4] = *(const float4*)(fb + r * 68 + cp * 8 + 4);
        *(float4*)&pp[0] = *(const float4*)(io + (size_t)row * 64 + cp * 8);
        *(float4*)&pp[4] = *(const float4*)(io + (size_t)row * 64 + cp * 8 + 4);
#pragma unroll
        for (int j = 0; j < 8; ++j) {
          int c = cp * 8 + j;
          o[j] = t[j] + fmaf(pp[j], affB[c], affB[64 + c]);
        }
        *(float4*)(y + (size_t)row * 64 + cp * 8) = *(const float4*)&o[0];
        *(float4*)(y + (size_t)row * 64 + cp * 8 + 4) = *(const float4*)&o[4];
      }
    }
  }
  if constexpr (MODE != 2) {
    if (tid < 128) {
      int which = tid >> 6, c = tid & 63;
      float v = sred[0][which * 64 + c] + sred[1][which * 64 + c] +
                sred[2][which * 64 + c] + sred[3][which * 64 + c];
      atomicAdd(&st[(blockIdx.x & (NREP - 1)) * 128 + which * 64 + c], v);
    }
  }
}

// prep kernel (fallback tiers)
__global__ void prep_all(const float* __restrict__ feat, const float* __restrict__ w1,
                         const float* __restrict__ w2, u16* __restrict__ wf,
                         u16* __restrict__ F, float* __restrict__ st,
                         int cvt_blocks) {
  const int bid = blockIdx.x, tid = threadIdx.x;
  if (bid < cvt_blocks) {
    int i8 = (bid * 256 + tid) * 8;
    if (i8 < NVOX * 64) {
      uint4 a = *(const uint4*)(feat + i8);
      uint4 b = *(const uint4*)(feat + i8 + 4);
      *(uint4*)(F + i8) = cvt8(a, b);
    }
    return;
  }
  int rb = bid - cvt_blocks;
  if (rb < 288) {
    int e = rb * 256 + tid;
    int slot = e / 36864, r = e % 36864;
    int k = r >> 12, rr = r & 4095;
    int frag = rr >> 9, lane = (rr >> 3) & 63, j = rr & 7;
    int ks = frag >> 1, ct = frag & 1;
    int cin = ks * 16 + (lane >> 5) * 8 + j;
    int cout = ct * 32 + (lane & 31);
    const float* src = slot ? w2 : w1;
    wf[e] = f2bf(src[k * 4096 + cin * 64 + cout]);
    return;
  }
  for (int i = tid; i < 4 * STG; i += 256) st[i] = 0.f;
}

// fold both BN stages into both second-conv weights (fallback tiers)
__global__ void wscale2(const float* __restrict__ wA, float* __restrict__ stpA,
                        const float* __restrict__ gA, const float* __restrict__ bA,
                        u16* __restrict__ dA,
                        const float* __restrict__ wB, float* __restrict__ stpB,
                        const float* __restrict__ gB, const float* __restrict__ bB,
                        u16* __restrict__ dB) {
  __shared__ float sc[64], sh[64];
  const int tid = threadIdx.x;
  const bool hB = (blockIdx.x >= 180);
  const float* wraw = hB ? wB : wA;
  float* stp = hB ? stpB : stpA;
  const float* g = hB ? gB : gA;
  const float* b = hB ? bB : bA;
  u16* dst = hB ? dB : dA;
  const int blk = hB ? blockIdx.x - 180 : blockIdx.x;
  if (tid < 64) {
    float a, h;
    bn_from_replicas(stp, g, b, tid, &a, &h);
    sc[tid] = a; sh[tid] = h;
    if (blk == 0) { stp[NREP * 128 + tid] = a; stp[NREP * 128 + 64 + tid] = h; }
  }
  __syncthreads();
  int e = blk * 256 + tid;
  int k = e / 5120, r = e % 5120;
  int frag = r >> 9, lane = (r >> 3) & 63, j = r & 7;
  int ks = frag >> 1, ct = frag & 1;
  int cout = ct * 32 + (lane & 31);
  u16 val = 0;
  if (ks < 4) {
    int cin = ks * 16 + (lane >> 5) * 8 + j;
    val = f2bf(sc[cin] * wraw[k * 4096 + cin * 64 + cout]);
  } else if (((lane >> 5) == 0) && j == 0) {
    float acc = 0.f;
    for (int c = 0; c < 64; ++c) acc += sh[c] * wraw[k * 4096 + c * 64 + cout];
    val = f2bf(acc);
  }
  dst[e] = val;
}

// both output-BN affines (fallback tiers)
__global__ void finalize2(float* __restrict__ stA, const float* __restrict__ gA,
                          const float* __restrict__ bA, float* __restrict__ stB,
                          const float* __restrict__ gB, const float* __restrict__ bB) {
  int t = threadIdx.x;
  float* stp = (t < 64) ? stA : stB;
  const float* g = (t < 64) ? gA : gB;
  const float* b = (t < 64) ? bA : bB;
  int c = t & 63;
  if (t < 128) {
    float a, h;
    bn_from_replicas(stp, g, b, c, &a, &h);
    stp[NREP * 128 + c] = a;
    stp[NREP * 128 + 64 + c] = h;
  }
}

// io (fp32, in place) = affB(io) + affD(y3 bf16)   (fallback tiers)
__global__ void final_add(const u16* __restrict__ y3, float* io,
                          const float* __restrict__ affB, const float* __restrict__ affD) {
  int i8 = (blockIdx.x * 256 + threadIdx.x) * 8;
  if (i8 < NVOX * 64) {
    float a[8];
    *(float4*)&a[0] = *(const float4*)(io + i8);
    *(float4*)&a[4] = *(const float4*)(io + i8 + 4);
    uint4 vd = *(const uint4*)(y3 + i8);
    const u16* pd = (const u16*)&vd;
    int cb = i8 & 63;
    float o[8];
#pragma unroll
    for (int j = 0; j < 8; ++j) {
      int c = cb + j;
      o[j] = fmaf(a[j], affB[c], affB[64 + c]) + fmaf(bf2f(pd[j]), affD[c], affD[64 + c]);
    }
    *(float4*)(io + i8) = *(const float4*)&o[0];
    *(float4*)(io + i8 + 4) = *(const float4*)&o[4];
  }
}

extern "C" void kernel_launch(void* const* d_in, const int* in_sizes, int n_in,
                              void* d_out, int out_size, void* d_ws, size_t ws_size,
                              hipStream_t stream) {
  const float* feat = (const float*)d_in[0];
  const float* w1 = (const float*)d_in[1];
  const float* w1_2 = (const float*)d_in[2];
  const float* w2 = (const float*)d_in[3];
  const float* w3 = (const float*)d_in[4];
  const float* g0 = (const float*)d_in[5];
  const float* b0 = (const float*)d_in[6];
  const float* g0_2 = (const float*)d_in[7];
  const float* b0_2 = (const float*)d_in[8];
  const float* g1 = (const float*)d_in[9];
  const float* b1 = (const float*)d_in[10];
  const float* g2 = (const float*)d_in[11];
  const float* b2 = (const float*)d_in[12];
  const int* nbr13 = (const int*)d_in[13];
  const int* nbr31 = (const int*)d_in[14];
  float* out = (float*)d_out;

  char* ws = (char*)d_ws;
  float* st = (float*)ws;                         // 4 stages x 4224 f = 67,584 B
  u16* wf = (u16*)(ws + 67584);                   // 331,776 B of fragments
  u16* s0 = wf;                                   // w1 raw      (36,864 u16)
  u16* s1 = wf + 36864;                           // w2 raw
  u16* s2 = wf + 73728;                           // w1_2 folded (46,080 u16)
  u16* s3 = wf + 119808;                          // w3 folded
  u16* F = (u16*)(ws + 399488);                   // feat bf16 / Y3, 25.6 MB
  u16* A1 = F + (size_t)NVOX * 64;                // 25.6 MB
  u16* A2 = A1 + (size_t)NVOX * 64;               // 25.6 MB (fused plan only)
  const size_t base_sz = 399488;
  const size_t need_fused = base_sz + 3ull * NVOX * 64 * 2;
  const size_t need_serial = base_sz + 2ull * NVOX * 64 * 2;

  float* st0 = st, *st1 = st + STG, *st2 = st + 2 * STG, *st3 = st + 3 * STG;

  if (ws_size >= need_fused) {
    static int coopGrid = 0;
    if (coopGrid == 0) {
      int maxb = 0;
      hipOccupancyMaxActiveBlocksPerMultiprocessor(&maxb, mega, 256, 0);
      if (maxb <= 0) maxb = 4;   // conservative fallback
      int dev = 0;
      hipGetDevice(&dev);
      hipDeviceProp_t prop;
      int ncu = 256;
      if (hipGetDeviceProperties(&prop, dev) == hipSuccess && prop.multiProcessorCount > 0)
        ncu = prop.multiProcessorCount;
      coopGrid = maxb * ncu;
      if (coopGrid > 6539) coopGrid = 6539;
    }
    MegaParams p;
    p.feat = feat; p.w1 = w1; p.w1_2 = w1_2; p.w2 = w2; p.w3 = w3;
    p.g0 = g0; p.b0 = b0; p.g0_2 = g0_2; p.b0_2 = b0_2;
    p.g1 = g1; p.b1 = b1; p.g2 = g2; p.b2 = b2;
    p.nbr13 = nbr13; p.nbr31 = nbr31; p.out = out;
    p.stats = st; p.st0 = st0; p.st1 = st1; p.st2 = st2; p.st3 = st3;
    p.wf = wf; p.s0 = s0; p.s1 = s1; p.s2 = s2; p.s3 = s3;
    p.F = F; p.A1 = A1; p.A2 = A2;
    void* kargs[] = {(void*)&p};
    hipLaunchCooperativeKernel((const void*)mega, dim3(coopGrid), dim3(256),
                               kargs, 0, stream);
  } else if (ws_size >= need_serial) {
    prep_all<<<6539, 256, 0, stream>>>(feat, w1, w2, wf, F, st, 6250);
    conv_k<false, false, 0><<<NBLK, 256, 0, stream>>>(F, nbr13, s0, A1, st0, nullptr, nullptr, nullptr);
    wscale2<<<180, 256, 0, stream>>>(w1_2, st0, g0, b0, s2, w3, st2, g1, b1, s3);
    conv_k<false, true, 3><<<NBLK, 256, 0, stream>>>(A1, nbr31, s2, out, st1, nullptr, nullptr, nullptr);
    conv_k<false, false, 0><<<NBLK, 256, 0, stream>>>(F, nbr31, s1, A1, st2, nullptr, nullptr, nullptr);
    wscale2<<<360, 256, 0, stream>>>(w1_2, st0, g0, b0, s2, w3, st2, g1, b1, s3);
    conv_k<false, true, 0><<<NBLK, 256, 0, stream>>>(A1, nbr13, s3, F, st3, nullptr, nullptr, nullptr);
    finalize2<<<1, 128, 0, stream>>>(st1, g0_2, b0_2, st3, g2, b2);
    final_add<<<6250, 256, 0, stream>>>(F, out, st1 + NREP * 128, st3 + NREP * 128);
  } else {
    // minimal-ws: recompute path
    u16* Az = F;
    prep_all<<<289, 256, 0, stream>>>(feat, w1, w2, wf, nullptr, st, 0);
    conv_k<true, false, 0><<<NBLK, 256, 0, stream>>>(feat, nbr13, s0, Az, st0, nullptr, nullptr, nullptr);
    wscale2<<<180, 256, 0, stream>>>(w1_2, st0, g0, b0, s2, w3, st2, g1, b1, s3);
    conv_k<false, true, 3><<<NBLK, 256, 0, stream>>>(Az, nbr31, s2, out, st1, nullptr, nullptr, nullptr);
    finalize2<<<1, 128, 0, stream>>>(st1, g0_2, b0_2, st3, g2, b2);
    conv_k<true, false, 0><<<NBLK, 256, 0, stream>>>(feat, nbr31, s1, Az, st2, nullptr, nullptr, nullptr);
    wscale2<<<360, 256, 0, stream>>>(w1_2, st0, g0, b0, s2, w3, st2, g1, b1, s3);
    conv_k<false, true, 1><<<NBLK, 256, 0, stream>>>(Az, nbr13, s3, nullptr, st3, nullptr, nullptr, nullptr);
    finalize2<<<1, 128, 0, stream>>>(st1, g0_2, b0_2, st3, g2, b2);
    conv_k<false, true, 2><<<NBLK, 256, 0, stream>>>(Az, nbr13, s3, out, nullptr, out,
                                                     st3 + NREP * 128, st1 + NREP * 128);
  }
}

// Round 9
// 308.043 us; speedup vs baseline: 2.4161x; 2.4161x over previous
//
#include <hip/hip_runtime.h>

#define NVOX 200000
#define TM 128
#define NBLK 1563   // ceil(200000/128)
#define NVIRT (2 * NBLK)
#define CGRID 1536  // conv grid: 6 blocks/CU x 256 CU, grid-stride over NVIRT
#define SGRID 2048  // streaming-pass grid (Guideline 11: cap + grid-stride)
#define NREP 32     // stats-accumulator replicas
#define STG 4224    // floats per stage: 32*128 replicas + 64 scale + 64 shift

typedef unsigned short u16;
typedef unsigned int u32;
typedef __bf16 bf16x8 __attribute__((ext_vector_type(8)));
typedef float f32x16 __attribute__((ext_vector_type(16)));

__device__ __forceinline__ float bf2f(u16 h) { return __uint_as_float(((u32)h) << 16); }
__device__ __forceinline__ u16 f2bf(float x) {
  u32 u = __float_as_uint(x);
  u32 r = u + 0x7fffu + ((u >> 16) & 1u);   // RNE
  return (u16)(r >> 16);
}
__device__ __forceinline__ uint4 cvt8(uint4 a, uint4 b) {
  const float* fa = (const float*)&a;
  const float* fb = (const float*)&b;
  uint4 r;
  u16* q = (u16*)&r;
#pragma unroll
  for (int j = 0; j < 4; ++j) { q[j] = f2bf(fa[j]); q[4 + j] = f2bf(fb[j]); }
  return r;
}

__device__ __forceinline__ void bn_from_replicas(const float* stp, const float* g,
                                                 const float* b, int c,
                                                 float* sc, float* sh) {
  float s = 0.f, q = 0.f;
#pragma unroll
  for (int r = 0; r < NREP; ++r) {
    s += stp[r * 128 + c];
    q += stp[r * 128 + 64 + c];
  }
  const float invn = 1.0f / (float)NVOX;
  float mean = s * invn;
  float var = q * invn - mean * mean;
  float sca = g[c] * rsqrtf(var + 1e-5f);
  *sc = sca;
  *sh = b[c] - mean * sca;
}

// ---------------------------------------------------------------------------
// Round 15: r6 bodies, Guideline-11 grids.  No cooperative sync (mega's
// grid.sync cost ~200us each on 8 XCDs).  conv_fused: 1536 resident blocks
// grid-stride 3126 virtual tiles (2/block, zero relaunch, ramp amortized).
// prep/final: 2048-block grid-stride instead of 6.5k one-shot blocks.
// PHASE 0 (convA): raw weights; both streams -> bf16 + stats.
// PHASE 1 (convB): folded weights (+bias K-step); stream A -> fp32 out + stats,
//                  stream B -> bf16 + stats.
// ---------------------------------------------------------------------------
template <int PHASE>
__global__ __launch_bounds__(256, 6)
void conv_fused(const u16* __restrict__ inA, const u16* __restrict__ inB,
                const int* __restrict__ nbrA, const int* __restrict__ nbrB,
                const u16* __restrict__ wfA, const u16* __restrict__ wfB,
                void* yA, void* yB, float* __restrict__ stA, float* __restrict__ stB) {
  __shared__ __align__(16) float fb4[64 * 68];   // 17,408 B (u16 alias [64][72])
  __shared__ float sred[4][128];

  const int tid = threadIdx.x;
  const int wv = tid >> 6;
  const int lane = tid & 63;
  const int lrow = lane & 31;
  const int lq = lane >> 5;
  constexpr bool FOLDED = (PHASE == 1);
  constexpr int KSTRIDE = FOLDED ? 5120 : 4096;

  for (int bid = blockIdx.x; bid < NVIRT; bid += gridDim.x) {
    const bool hB = (bid >= NBLK);
    const int blk = hB ? bid - NBLK : bid;
    const u16* f = hB ? inB : inA;
    const int* nbr = hB ? nbrB : nbrA;
    const u16* wf = hB ? wfB : wfA;
    float* st = hB ? stB : stA;

    const int base = blk * TM;
    const int gr = base + wv * 32 + lrow;

    int ids[9];
#pragma unroll
    for (int j = 0; j < 9; ++j) ids[j] = (gr < NVOX) ? nbr[gr * 9 + j] : NVOX;

    f32x16 acc0 = {0.f, 0.f, 0.f, 0.f, 0.f, 0.f, 0.f, 0.f,
                   0.f, 0.f, 0.f, 0.f, 0.f, 0.f, 0.f, 0.f};
    f32x16 acc1 = acc0;

#pragma unroll
    for (int k = 0; k < 9; ++k) {
      if (k != 4) {
        if (__ballot(ids[k] < NVOX) == 0ull) continue;
      }
      const int id = ids[k];
      const bool ok = id < NVOX;
      uint4 af[4];
      const u16* p = f + (size_t)id * 64 + lq * 8;
#pragma unroll
      for (int ksi = 0; ksi < 4; ++ksi) {
        uint4 v = make_uint4(0u, 0u, 0u, 0u);
        if (ok) v = *(const uint4*)(p + ksi * 16);
        af[ksi] = v;
      }
      const u16* wb = wf + k * KSTRIDE;
#pragma unroll
      for (int ksi = 0; ksi < 4; ++ksi) {
        bf16x8 a = __builtin_bit_cast(bf16x8, af[ksi]);
        bf16x8 b0 = __builtin_bit_cast(bf16x8, *(const uint4*)(wb + (ksi * 2) * 512 + lane * 8));
        bf16x8 b1 = __builtin_bit_cast(bf16x8, *(const uint4*)(wb + (ksi * 2 + 1) * 512 + lane * 8));
        acc0 = __builtin_amdgcn_mfma_f32_32x32x16_bf16(a, b0, acc0, 0, 0, 0);
        acc1 = __builtin_amdgcn_mfma_f32_32x32x16_bf16(a, b1, acc1, 0, 0, 0);
      }
      if constexpr (FOLDED) {   // bias channel: A = 1[exists] at (lq=0, j=0)
        uint4 a4 = make_uint4(0u, 0u, 0u, 0u);
        if (lq == 0 && ok) ((u16*)&a4)[0] = 0x3F80u;
        bf16x8 a = __builtin_bit_cast(bf16x8, a4);
        bf16x8 b0 = __builtin_bit_cast(bf16x8, *(const uint4*)(wb + 8 * 512 + lane * 8));
        bf16x8 b1 = __builtin_bit_cast(bf16x8, *(const uint4*)(wb + 9 * 512 + lane * 8));
        acc0 = __builtin_amdgcn_mfma_f32_32x32x16_bf16(a, b0, acc0, 0, 0, 0);
        acc1 = __builtin_amdgcn_mfma_f32_32x32x16_bf16(a, b1, acc1, 0, 0, 0);
      }
    }

    // Epilogue. C/D (32x32): col = lane&31, row = (reg&3) + 8*(reg>>2) + 4*(lane>>5)
    const int cc0 = lrow, cc1 = 32 + lrow;
    float s0 = 0.f, q0 = 0.f, s1 = 0.f, q1 = 0.f;
    float vout[2][16];
#pragma unroll
    for (int r = 0; r < 16; ++r) {
      float v = acc0[r]; v = v > 0.f ? v : 0.01f * v;
      s0 += v; q0 += v * v; vout[0][r] = v;
      float w = acc1[r]; w = w > 0.f ? w : 0.01f * w;
      s1 += w; q1 += w * w; vout[1][r] = w;
    }
    s0 += __shfl_xor(s0, 32); q0 += __shfl_xor(q0, 32);
    s1 += __shfl_xor(s1, 32); q1 += __shfl_xor(q1, 32);
    if (lq == 0) {   // rows >= NVOX contribute exact 0
      sred[wv][lrow] = s0; sred[wv][32 + lrow] = s1;
      sred[wv][64 + lrow] = q0; sred[wv][96 + lrow] = q1;
    }

    const bool f32out = (PHASE == 1) && !hB;
    const int trow = tid >> 3, cp = tid & 7;
    u16* bb = (u16*)fb4;
#pragma unroll
    for (int h = 0; h < 2; ++h) {
      __syncthreads();
      if ((wv >> 1) == h) {
        const int lr = 32 * (wv & 1);
#pragma unroll
        for (int r = 0; r < 16; ++r) {
          int rowD = lr + (r & 3) + 8 * (r >> 2) + 4 * lq;
          if (f32out) {
            fb4[rowD * 68 + cc0] = vout[0][r];
            fb4[rowD * 68 + cc1] = vout[1][r];
          } else {
            bb[rowD * 72 + cc0] = f2bf(vout[0][r]);
            bb[rowD * 72 + cc1] = f2bf(vout[1][r]);
          }
        }
      }
      __syncthreads();
      if (f32out) {
        float* y = (float*)yA;
#pragma unroll
        for (int it = 0; it < 2; ++it) {
          int r = it * 32 + trow, row = base + 64 * h + r;
          if (row < NVOX) {
            *(float4*)(y + (size_t)row * 64 + cp * 8) = *(const float4*)(fb4 + r * 68 + cp * 8);
            *(float4*)(y + (size_t)row * 64 + cp * 8 + 4) = *(const float4*)(fb4 + r * 68 + cp * 8 + 4);
          }
        }
      } else {
        u16* y = (u16*)(hB ? yB : yA);
#pragma unroll
        for (int it = 0; it < 2; ++it) {
          int r = it * 32 + trow, row = base + 64 * h + r;
          if (row < NVOX)
            *(uint4*)(y + (size_t)row * 64 + cp * 8) = *(const uint4*)(bb + r * 72 + cp * 8);
        }
      }
    }
    if (tid < 128) {
      int which = tid >> 6, c = tid & 63;
      float v = sred[0][which * 64 + c] + sred[1][which * 64 + c] +
                sred[2][which * 64 + c] + sred[3][which * 64 + c];
      atomicAdd(&st[(bid & (NREP - 1)) * 128 + which * 64 + c], v);
    }
    __syncthreads();   // protect sred/fb4 reuse across grid-stride iterations
  }
}

// ---- round-6 serial conv (fallback tiers) ---------------------------------
template <bool IN_F32, bool FOLDED, int MODE>
__global__ __launch_bounds__(256, 4)
void conv_k(const void* __restrict__ fv, const int* __restrict__ nbr,
            const u16* __restrict__ wf, void* yv, float* __restrict__ st,
            float* io, const float* __restrict__ affD,
            const float* __restrict__ affB) {
  __shared__ __align__(16) float fb[128 * 68];
  __shared__ float sred[4][128];

  const int tid = threadIdx.x;
  const int wv = tid >> 6;
  const int lane = tid & 63;
  const int lrow = lane & 31;
  const int lq = lane >> 5;
  const int base = blockIdx.x * TM;
  const int gr = base + wv * 32 + lrow;

  int ids[9];
#pragma unroll
  for (int j = 0; j < 9; ++j) ids[j] = (gr < NVOX) ? nbr[gr * 9 + j] : NVOX;

  f32x16 acc0 = {0.f, 0.f, 0.f, 0.f, 0.f, 0.f, 0.f, 0.f,
                 0.f, 0.f, 0.f, 0.f, 0.f, 0.f, 0.f, 0.f};
  f32x16 acc1 = acc0;
  constexpr int KSTRIDE = FOLDED ? 5120 : 4096;

#pragma unroll
  for (int k = 0; k < 9; ++k) {
    if (k != 4) {
      if (__ballot(ids[k] < NVOX) == 0ull) continue;
    }
    const int id = ids[k];
    const bool ok = id < NVOX;
    uint4 af[4];
    if constexpr (IN_F32) {
      const float* p = (const float*)fv + (size_t)id * 64 + lq * 8;
#pragma unroll
      for (int ksi = 0; ksi < 4; ++ksi) {
        uint4 v0 = make_uint4(0u, 0u, 0u, 0u), v1 = v0;
        if (ok) { v0 = *(const uint4*)(p + ksi * 16); v1 = *(const uint4*)(p + ksi * 16 + 4); }
        af[ksi] = cvt8(v0, v1);
      }
    } else {
      const u16* p = (const u16*)fv + (size_t)id * 64 + lq * 8;
#pragma unroll
      for (int ksi = 0; ksi < 4; ++ksi) {
        uint4 v = make_uint4(0u, 0u, 0u, 0u);
        if (ok) v = *(const uint4*)(p + ksi * 16);
        af[ksi] = v;
      }
    }
    const u16* wb = wf + k * KSTRIDE;
#pragma unroll
    for (int ksi = 0; ksi < 4; ++ksi) {
      bf16x8 a = __builtin_bit_cast(bf16x8, af[ksi]);
      bf16x8 b0 = __builtin_bit_cast(bf16x8, *(const uint4*)(wb + (ksi * 2) * 512 + lane * 8));
      bf16x8 b1 = __builtin_bit_cast(bf16x8, *(const uint4*)(wb + (ksi * 2 + 1) * 512 + lane * 8));
      acc0 = __builtin_amdgcn_mfma_f32_32x32x16_bf16(a, b0, acc0, 0, 0, 0);
      acc1 = __builtin_amdgcn_mfma_f32_32x32x16_bf16(a, b1, acc1, 0, 0, 0);
    }
    if constexpr (FOLDED) {
      uint4 a4 = make_uint4(0u, 0u, 0u, 0u);
      if (lq == 0 && ok) ((u16*)&a4)[0] = 0x3F80u;
      bf16x8 a = __builtin_bit_cast(bf16x8, a4);
      bf16x8 b0 = __builtin_bit_cast(bf16x8, *(const uint4*)(wb + 8 * 512 + lane * 8));
      bf16x8 b1 = __builtin_bit_cast(bf16x8, *(const uint4*)(wb + 9 * 512 + lane * 8));
      acc0 = __builtin_amdgcn_mfma_f32_32x32x16_bf16(a, b0, acc0, 0, 0, 0);
      acc1 = __builtin_amdgcn_mfma_f32_32x32x16_bf16(a, b1, acc1, 0, 0, 0);
    }
  }

  const int cc0 = lrow, cc1 = 32 + lrow;
  float aD0 = 0.f, aD1 = 0.f, hD0 = 0.f, hD1 = 0.f;
  if constexpr (MODE == 2) {
    aD0 = affD[cc0]; hD0 = affD[64 + cc0];
    aD1 = affD[cc1]; hD1 = affD[64 + cc1];
  }
  float s0 = 0.f, q0 = 0.f, s1 = 0.f, q1 = 0.f;
  float vout[2][16];
#pragma unroll
  for (int r = 0; r < 16; ++r) {
    float v = acc0[r]; v = v > 0.f ? v : 0.01f * v;
    s0 += v; q0 += v * v; vout[0][r] = v;
    float w = acc1[r]; w = w > 0.f ? w : 0.01f * w;
    s1 += w; q1 += w * w; vout[1][r] = w;
  }
  if constexpr (MODE != 2) {
    s0 += __shfl_xor(s0, 32); q0 += __shfl_xor(q0, 32);
    s1 += __shfl_xor(s1, 32); q1 += __shfl_xor(q1, 32);
    if (lq == 0) {
      sred[wv][lrow] = s0; sred[wv][32 + lrow] = s1;
      sred[wv][64 + lrow] = q0; sred[wv][96 + lrow] = q1;
    }
  }
  if constexpr (MODE == 0) {
    u16* bb = (u16*)fb;
#pragma unroll
    for (int r = 0; r < 16; ++r) {
      int rowD = 32 * wv + (r & 3) + 8 * (r >> 2) + 4 * lq;
      bb[rowD * 72 + cc0] = f2bf(vout[0][r]);
      bb[rowD * 72 + cc1] = f2bf(vout[1][r]);
    }
  } else if constexpr (MODE == 2 || MODE == 3) {
#pragma unroll
    for (int r = 0; r < 16; ++r) {
      int rowD = 32 * wv + (r & 3) + 8 * (r >> 2) + 4 * lq;
      float v0 = vout[0][r], v1 = vout[1][r];
      if constexpr (MODE == 2) { v0 = fmaf(v0, aD0, hD0); v1 = fmaf(v1, aD1, hD1); }
      fb[rowD * 68 + cc0] = v0;
      fb[rowD * 68 + cc1] = v1;
    }
  }
  __syncthreads();

  const int trow = tid >> 3, cp = tid & 7;
  if constexpr (MODE == 0) {
    u16* y = (u16*)yv;
    const u16* bb = (const u16*)fb;
#pragma unroll
    for (int it = 0; it < 4; ++it) {
      int r = it * 32 + trow, row = base + r;
      if (row < NVOX)
        *(uint4*)(y + (size_t)row * 64 + cp * 8) = *(const uint4*)(bb + r * 72 + cp * 8);
    }
  }
  if constexpr (MODE == 3) {
    float* y = (float*)yv;
#pragma unroll
    for (int it = 0; it < 4; ++it) {
      int r = it * 32 + trow, row = base + r;
      if (row < NVOX) {
        *(float4*)(y + (size_t)row * 64 + cp * 8) = *(const float4*)(fb + r * 68 + cp * 8);
        *(float4*)(y + (size_t)row * 64 + cp * 8 + 4) = *(const float4*)(fb + r * 68 + cp * 8 + 4);
      }
    }
  }
  if constexpr (MODE == 2) {
    float* y = (float*)yv;
#pragma unroll
    for (int it = 0; it < 4; ++it) {
      int r = it * 32 + trow, row = base + r;
      if (row < NVOX) {
        float t[8], pp[8], o[8];
        *(float4*)&t[0] = *(const float4*)(fb + r * 68 + cp * 8);
        *(float4*)&t[4] = *(const float4*)(fb + r * 68 + cp * 8 + 4);
        *(float4*)&pp[0] = *(const float4*)(io + (size_t)row * 64 + cp * 8);
        *(float4*)&pp[4] = *(const float4*)(io + (size_t)row * 64 + cp * 8 + 4);
#pragma unroll
        for (int j = 0; j < 8; ++j) {
          int c = cp * 8 + j;
          o[j] = t[j] + fmaf(pp[j], affB[c], affB[64 + c]);
        }
        *(float4*)(y + (size_t)row * 64 + cp * 8) = *(const float4*)&o[0];
        *(float4*)(y + (size_t)row * 64 + cp * 8 + 4) = *(const float4*)&o[4];
      }
    }
  }
  if constexpr (MODE != 2) {
    if (tid < 128) {
      int which = tid >> 6, c = tid & 63;
      float v = sred[0][which * 64 + c] + sred[1][which * 64 + c] +
                sred[2][which * 64 + c] + sred[3][which * 64 + c];
      atomicAdd(&st[(blockIdx.x & (NREP - 1)) * 128 + which * 64 + c], v);
    }
  }
}

// prep: grid-stride over [0,6250) cvt | [6250,6538) frags | 6538 stats-zero
__global__ void prep_all(const float* __restrict__ feat, const float* __restrict__ w1,
                         const float* __restrict__ w2, u16* __restrict__ wf,
                         u16* __restrict__ F, float* __restrict__ st,
                         int cvt_blocks) {
  const int tid = threadIdx.x;
  const int nvirt = cvt_blocks + 288 + 1;
  for (int bid = blockIdx.x; bid < nvirt; bid += gridDim.x) {
    if (bid < cvt_blocks) {
      int i8 = (bid * 256 + tid) * 8;
      if (i8 < NVOX * 64) {
        uint4 a = *(const uint4*)(feat + i8);
        uint4 b = *(const uint4*)(feat + i8 + 4);
        *(uint4*)(F + i8) = cvt8(a, b);
      }
      continue;
    }
    int rb = bid - cvt_blocks;
    if (rb < 288) {   // raw frags: [slot 0|1][k][ks*2+ct][lane][j]
      int e = rb * 256 + tid;
      int slot = e / 36864, r = e % 36864;
      int k = r >> 12, rr = r & 4095;
      int frag = rr >> 9, lane = (rr >> 3) & 63, j = rr & 7;
      int ks = frag >> 1, ct = frag & 1;
      int cin = ks * 16 + (lane >> 5) * 8 + j;
      int cout = ct * 32 + (lane & 31);
      const float* src = slot ? w2 : w1;
      wf[e] = f2bf(src[k * 4096 + cin * 64 + cout]);
      continue;
    }
    for (int i = tid; i < 4 * STG; i += 256) st[i] = 0.f;
  }
}

// fold both BN stages into both second-conv weights (one dispatch, 360 blocks)
__global__ void wscale2(const float* __restrict__ wA, float* __restrict__ stpA,
                        const float* __restrict__ gA, const float* __restrict__ bA,
                        u16* __restrict__ dA,
                        const float* __restrict__ wB, float* __restrict__ stpB,
                        const float* __restrict__ gB, const float* __restrict__ bB,
                        u16* __restrict__ dB) {
  __shared__ float sc[64], sh[64];
  const int tid = threadIdx.x;
  const bool hB = (blockIdx.x >= 180);
  const float* wraw = hB ? wB : wA;
  float* stp = hB ? stpB : stpA;
  const float* g = hB ? gB : gA;
  const float* b = hB ? bB : bA;
  u16* dst = hB ? dB : dA;
  const int blk = hB ? blockIdx.x - 180 : blockIdx.x;
  if (tid < 64) {
    float a, h;
    bn_from_replicas(stp, g, b, tid, &a, &h);
    sc[tid] = a; sh[tid] = h;
    if (blk == 0) { stp[NREP * 128 + tid] = a; stp[NREP * 128 + 64 + tid] = h; }
  }
  __syncthreads();
  int e = blk * 256 + tid;   // [0, 46080)
  int k = e / 5120, r = e % 5120;
  int frag = r >> 9, lane = (r >> 3) & 63, j = r & 7;
  int ks = frag >> 1, ct = frag & 1;
  int cout = ct * 32 + (lane & 31);
  u16 val = 0;
  if (ks < 4) {
    int cin = ks * 16 + (lane >> 5) * 8 + j;
    val = f2bf(sc[cin] * wraw[k * 4096 + cin * 64 + cout]);
  } else if (((lane >> 5) == 0) && j == 0) {
    float acc = 0.f;
    for (int c = 0; c < 64; ++c) acc += sh[c] * wraw[k * 4096 + c * 64 + cout];
    val = f2bf(acc);
  }
  dst[e] = val;
}

// both output-BN affines in one tiny dispatch (fallback tiers)
__global__ void finalize2(float* __restrict__ stA, const float* __restrict__ gA,
                          const float* __restrict__ bA, float* __restrict__ stB,
                          const float* __restrict__ gB, const float* __restrict__ bB) {
  int t = threadIdx.x;
  float* stp = (t < 64) ? stA : stB;
  const float* g = (t < 64) ? gA : gB;
  const float* b = (t < 64) ? bA : bB;
  int c = t & 63;
  if (t < 128) {
    float a, h;
    bn_from_replicas(stp, g, b, c, &a, &h);
    stp[NREP * 128 + c] = a;
    stp[NREP * 128 + 64 + c] = h;
  }
}

// io (fp32, in place) = affB(io) + affD(y3 bf16)   (fallback tiers)
__global__ void final_add(const u16* __restrict__ y3, float* io,
                          const float* __restrict__ affB, const float* __restrict__ affD) {
  int i8 = (blockIdx.x * 256 + threadIdx.x) * 8;
  if (i8 < NVOX * 64) {
    float a[8];
    *(float4*)&a[0] = *(const float4*)(io + i8);
    *(float4*)&a[4] = *(const float4*)(io + i8 + 4);
    uint4 vd = *(const uint4*)(y3 + i8);
    const u16* pd = (const u16*)&vd;
    int cb = i8 & 63;
    float o[8];
#pragma unroll
    for (int j = 0; j < 8; ++j) {
      int c = cb + j;
      o[j] = fmaf(a[j], affB[c], affB[64 + c]) + fmaf(bf2f(pd[j]), affD[c], affD[64 + c]);
    }
    *(float4*)(io + i8) = *(const float4*)&o[0];
    *(float4*)(io + i8 + 4) = *(const float4*)&o[4];
  }
}

// fused tier: finalize2 + final_add merged, grid-stride (affines hoisted)
__global__ void final_add2(const u16* __restrict__ y3, float* io,
                           float* __restrict__ stB, const float* __restrict__ gB,
                           const float* __restrict__ bB,
                           float* __restrict__ stD, const float* __restrict__ gD,
                           const float* __restrict__ bD) {
  __shared__ float aff[4][64];   // [B scale][B shift][D scale][D shift]
  const int t = threadIdx.x;
  if (t < 128) {
    float a, h;
    if (t < 64) { bn_from_replicas(stB, gB, bB, t, &a, &h); aff[0][t] = a; aff[1][t] = h; }
    else { int c = t - 64; bn_from_replicas(stD, gD, bD, c, &a, &h); aff[2][c] = a; aff[3][c] = h; }
  }
  __syncthreads();
  for (int b = blockIdx.x; b < 6250; b += gridDim.x) {
    int i8 = (b * 256 + t) * 8;
    if (i8 < NVOX * 64) {
      float a[8];
      *(float4*)&a[0] = *(const float4*)(io + i8);
      *(float4*)&a[4] = *(const float4*)(io + i8 + 4);
      uint4 vd = *(const uint4*)(y3 + i8);
      const u16* pd = (const u16*)&vd;
      int cb = i8 & 63;
      float o[8];
#pragma unroll
      for (int j = 0; j < 8; ++j) {
        int c = cb + j;
        o[j] = fmaf(a[j], aff[0][c], aff[1][c]) + fmaf(bf2f(pd[j]), aff[2][c], aff[3][c]);
      }
      *(float4*)(io + i8) = *(const float4*)&o[0];
      *(float4*)(io + i8 + 4) = *(const float4*)&o[4];
    }
  }
}

extern "C" void kernel_launch(void* const* d_in, const int* in_sizes, int n_in,
                              void* d_out, int out_size, void* d_ws, size_t ws_size,
                              hipStream_t stream) {
  const float* feat = (const float*)d_in[0];
  const float* w1 = (const float*)d_in[1];
  const float* w1_2 = (const float*)d_in[2];
  const float* w2 = (const float*)d_in[3];
  const float* w3 = (const float*)d_in[4];
  const float* g0 = (const float*)d_in[5];
  const float* b0 = (const float*)d_in[6];
  const float* g0_2 = (const float*)d_in[7];
  const float* b0_2 = (const float*)d_in[8];
  const float* g1 = (const float*)d_in[9];
  const float* b1 = (const float*)d_in[10];
  const float* g2 = (const float*)d_in[11];
  const float* b2 = (const float*)d_in[12];
  const int* nbr13 = (const int*)d_in[13];
  const int* nbr31 = (const int*)d_in[14];
  float* out = (float*)d_out;

  char* ws = (char*)d_ws;
  float* st = (float*)ws;                         // 4 stages x 4224 f = 67,584 B
  u16* wf = (u16*)(ws + 67584);                   // 331,776 B of fragments
  u16* s0 = wf;                                   // w1 raw      (36,864 u16)
  u16* s1 = wf + 36864;                           // w2 raw
  u16* s2 = wf + 73728;                           // w1_2 folded (46,080 u16)
  u16* s3 = wf + 119808;                          // w3 folded
  u16* F = (u16*)(ws + 399488);                   // feat bf16 / Y3, 25.6 MB
  u16* A1 = F + (size_t)NVOX * 64;                // 25.6 MB
  u16* A2 = A1 + (size_t)NVOX * 64;               // 25.6 MB (fused plan only)
  const size_t base_sz = 399488;
  const size_t need_fused = base_sz + 3ull * NVOX * 64 * 2;
  const size_t need_serial = base_sz + 2ull * NVOX * 64 * 2;

  float* st0 = st, *st1 = st + STG, *st2 = st + 2 * STG, *st3 = st + 3 * STG;

  if (ws_size >= need_fused) {
    prep_all<<<SGRID, 256, 0, stream>>>(feat, w1, w2, wf, F, st, 6250);
    // convA: conv1(F,nbr13,s0)->A1,st0  ||  conv2(F,nbr31,s1)->A2,st2
    conv_fused<0><<<CGRID, 256, 0, stream>>>(F, F, nbr13, nbr31, s0, s1,
                                             A1, A2, st0, st2);
    wscale2<<<360, 256, 0, stream>>>(w1_2, st0, g0, b0, s2, w3, st2, g1, b1, s3);
    // convB: conv1_2(A1,nbr31,s2)->out fp32,st1  ||  conv3(A2,nbr13,s3)->F bf16,st3
    conv_fused<1><<<CGRID, 256, 0, stream>>>(A1, A2, nbr31, nbr13, s2, s3,
                                             out, F, st1, st3);
    final_add2<<<SGRID, 256, 0, stream>>>(F, out, st1, g0_2, b0_2, st3, g2, b2);
  } else if (ws_size >= need_serial) {
    prep_all<<<SGRID, 256, 0, stream>>>(feat, w1, w2, wf, F, st, 6250);
    conv_k<false, false, 0><<<NBLK, 256, 0, stream>>>(F, nbr13, s0, A1, st0, nullptr, nullptr, nullptr);
    wscale2<<<180, 256, 0, stream>>>(w1_2, st0, g0, b0, s2, w3, st2, g1, b1, s3);
    conv_k<false, true, 3><<<NBLK, 256, 0, stream>>>(A1, nbr31, s2, out, st1, nullptr, nullptr, nullptr);
    conv_k<false, false, 0><<<NBLK, 256, 0, stream>>>(F, nbr31, s1, A1, st2, nullptr, nullptr, nullptr);
    wscale2<<<360, 256, 0, stream>>>(w1_2, st0, g0, b0, s2, w3, st2, g1, b1, s3);
    conv_k<false, true, 0><<<NBLK, 256, 0, stream>>>(A1, nbr13, s3, F, st3, nullptr, nullptr, nullptr);
    finalize2<<<1, 128, 0, stream>>>(st1, g0_2, b0_2, st3, g2, b2);
    final_add<<<6250, 256, 0, stream>>>(F, out, st1 + NREP * 128, st3 + NREP * 128);
  } else {
    // minimal-ws: recompute path
    u16* Az = F;
    prep_all<<<289, 256, 0, stream>>>(feat, w1, w2, wf, nullptr, st, 0);
    conv_k<true, false, 0><<<NBLK, 256, 0, stream>>>(feat, nbr13, s0, Az, st0, nullptr, nullptr, nullptr);
    wscale2<<<180, 256, 0, stream>>>(w1_2, st0, g0, b0, s2, w3, st2, g1, b1, s3);
    conv_k<false, true, 3><<<NBLK, 256, 0, stream>>>(Az, nbr31, s2, out, st1, nullptr, nullptr, nullptr);
    finalize2<<<1, 128, 0, stream>>>(st1, g0_2, b0_2, st3, g2, b2);
    conv_k<true, false, 0><<<NBLK, 256, 0, stream>>>(feat, nbr31, s1, Az, st2, nullptr, nullptr, nullptr);
    wscale2<<<360, 256, 0, stream>>>(w1_2, st0, g0, b0, s2, w3, st2, g1, b1, s3);
    conv_k<false, true, 1><<<NBLK, 256, 0, stream>>>(Az, nbr13, s3, nullptr, st3, nullptr, nullptr, nullptr);
    finalize2<<<1, 128, 0, stream>>>(st1, g0_2, b0_2, st3, g2, b2);
    conv_k<false, true, 2><<<NBLK, 256, 0, stream>>>(Az, nbr13, s3, out, nullptr, out,
                                                     st3 + NREP * 128, st1 + NREP * 128);
  }
}

// Round 10
// 259.537 us; speedup vs baseline: 2.8677x; 1.1869x over previous
//
#include <hip/hip_runtime.h>

#define NVOX 200000
#define TM 128
#define NBLK 1563   // ceil(200000/128)
#define NREP 32     // stats-accumulator replicas
#define STG 4224    // floats per stage: 32*128 replicas + 64 scale + 64 shift

typedef unsigned short u16;
typedef unsigned int u32;
typedef __bf16 bf16x8 __attribute__((ext_vector_type(8)));
typedef float f32x16 __attribute__((ext_vector_type(16)));

__device__ __forceinline__ float bf2f(u16 h) { return __uint_as_float(((u32)h) << 16); }
__device__ __forceinline__ u16 f2bf(float x) {
  u32 u = __float_as_uint(x);
  u32 r = u + 0x7fffu + ((u >> 16) & 1u);   // RNE
  return (u16)(r >> 16);
}
__device__ __forceinline__ uint4 cvt8(uint4 a, uint4 b) {
  const float* fa = (const float*)&a;
  const float* fb = (const float*)&b;
  uint4 r;
  u16* q = (u16*)&r;
#pragma unroll
  for (int j = 0; j < 4; ++j) { q[j] = f2bf(fa[j]); q[4 + j] = f2bf(fb[j]); }
  return r;
}

// ---------------------------------------------------------------------------
// FINAL (session-best, measured 258.09 us e2e = round 6 configuration).
// Fused conv pair: blocks [0,NBLK) run stream A, [NBLK,2*NBLK) stream B.
// K-loop: ballot-skip, exec-masked register-direct gathers, B-frags from L2.
// __launch_bounds__(256,6): ~24 waves/CU.  One-shot 2*NBLK grid (grid-stride
// and cooperative variants both measured slower: L2-residency loss / XCD
// grid.sync cost).  Neighbor row ordering is a random permutation, so the
// off-center gathers are uniform-random over 25.6 MB -> latency-bound floor;
// all scheduling/residency/occupancy levers measured +-0 or worse (R1-R9).
// PHASE 0 (convA): raw weights; both streams -> bf16 + stats.
// PHASE 1 (convB): folded weights (+bias K-step); stream A -> fp32 out + stats,
//                  stream B -> bf16 + stats.
// LDS: 64-row epilogue bounce (19.5 KB).
// ---------------------------------------------------------------------------
template <int PHASE>
__global__ __launch_bounds__(256, 6)
void conv_fused(const u16* __restrict__ inA, const u16* __restrict__ inB,
                const int* __restrict__ nbrA, const int* __restrict__ nbrB,
                const u16* __restrict__ wfA, const u16* __restrict__ wfB,
                void* yA, void* yB, float* __restrict__ stA, float* __restrict__ stB) {
  __shared__ __align__(16) float fb4[64 * 68];   // 17,408 B (u16 alias [64][72])
  __shared__ float sred[4][128];

  const int tid = threadIdx.x;
  const int bid = blockIdx.x;
  const bool hB = (bid >= NBLK);
  const int blk = hB ? bid - NBLK : bid;
  const u16* f = hB ? inB : inA;
  const int* nbr = hB ? nbrB : nbrA;
  const u16* wf = hB ? wfB : wfA;
  float* st = hB ? stB : stA;

  const int wv = tid >> 6;
  const int lane = tid & 63;
  const int lrow = lane & 31;
  const int lq = lane >> 5;
  const int base = blk * TM;
  const int gr = base + wv * 32 + lrow;

  int ids[9];
#pragma unroll
  for (int j = 0; j < 9; ++j) ids[j] = (gr < NVOX) ? nbr[gr * 9 + j] : NVOX;

  f32x16 acc0 = {0.f, 0.f, 0.f, 0.f, 0.f, 0.f, 0.f, 0.f,
                 0.f, 0.f, 0.f, 0.f, 0.f, 0.f, 0.f, 0.f};
  f32x16 acc1 = acc0;
  constexpr bool FOLDED = (PHASE == 1);
  constexpr int KSTRIDE = FOLDED ? 5120 : 4096;

#pragma unroll
  for (int k = 0; k < 9; ++k) {
    if (k != 4) {
      if (__ballot(ids[k] < NVOX) == 0ull) continue;
    }
    const int id = ids[k];
    const bool ok = id < NVOX;
    uint4 af[4];
    const u16* p = f + (size_t)id * 64 + lq * 8;
#pragma unroll
    for (int ksi = 0; ksi < 4; ++ksi) {
      uint4 v = make_uint4(0u, 0u, 0u, 0u);
      if (ok) v = *(const uint4*)(p + ksi * 16);
      af[ksi] = v;
    }
    const u16* wb = wf + k * KSTRIDE;
#pragma unroll
    for (int ksi = 0; ksi < 4; ++ksi) {
      bf16x8 a = __builtin_bit_cast(bf16x8, af[ksi]);
      bf16x8 b0 = __builtin_bit_cast(bf16x8, *(const uint4*)(wb + (ksi * 2) * 512 + lane * 8));
      bf16x8 b1 = __builtin_bit_cast(bf16x8, *(const uint4*)(wb + (ksi * 2 + 1) * 512 + lane * 8));
      acc0 = __builtin_amdgcn_mfma_f32_32x32x16_bf16(a, b0, acc0, 0, 0, 0);
      acc1 = __builtin_amdgcn_mfma_f32_32x32x16_bf16(a, b1, acc1, 0, 0, 0);
    }
    if constexpr (FOLDED) {   // bias channel: A = 1[exists] at (lq=0, j=0)
      uint4 a4 = make_uint4(0u, 0u, 0u, 0u);
      if (lq == 0 && ok) ((u16*)&a4)[0] = 0x3F80u;
      bf16x8 a = __builtin_bit_cast(bf16x8, a4);
      bf16x8 b0 = __builtin_bit_cast(bf16x8, *(const uint4*)(wb + 8 * 512 + lane * 8));
      bf16x8 b1 = __builtin_bit_cast(bf16x8, *(const uint4*)(wb + 9 * 512 + lane * 8));
      acc0 = __builtin_amdgcn_mfma_f32_32x32x16_bf16(a, b0, acc0, 0, 0, 0);
      acc1 = __builtin_amdgcn_mfma_f32_32x32x16_bf16(a, b1, acc1, 0, 0, 0);
    }
  }

  // Epilogue. C/D (32x32): col = lane&31, row = (reg&3) + 8*(reg>>2) + 4*(lane>>5)
  const int cc0 = lrow, cc1 = 32 + lrow;
  float s0 = 0.f, q0 = 0.f, s1 = 0.f, q1 = 0.f;
  float vout[2][16];
#pragma unroll
  for (int r = 0; r < 16; ++r) {
    float v = acc0[r]; v = v > 0.f ? v : 0.01f * v;
    s0 += v; q0 += v * v; vout[0][r] = v;
    float w = acc1[r]; w = w > 0.f ? w : 0.01f * w;
    s1 += w; q1 += w * w; vout[1][r] = w;
  }
  s0 += __shfl_xor(s0, 32); q0 += __shfl_xor(q0, 32);
  s1 += __shfl_xor(s1, 32); q1 += __shfl_xor(q1, 32);
  if (lq == 0) {   // rows >= NVOX contribute exact 0
    sred[wv][lrow] = s0; sred[wv][32 + lrow] = s1;
    sred[wv][64 + lrow] = q0; sred[wv][96 + lrow] = q1;
  }

  const bool f32out = (PHASE == 1) && !hB;
  const int trow = tid >> 3, cp = tid & 7;
  u16* bb = (u16*)fb4;
#pragma unroll
  for (int h = 0; h < 2; ++h) {
    __syncthreads();
    if ((wv >> 1) == h) {
      const int lr = 32 * (wv & 1);
#pragma unroll
      for (int r = 0; r < 16; ++r) {
        int rowD = lr + (r & 3) + 8 * (r >> 2) + 4 * lq;
        if (f32out) {
          fb4[rowD * 68 + cc0] = vout[0][r];
          fb4[rowD * 68 + cc1] = vout[1][r];
        } else {
          bb[rowD * 72 + cc0] = f2bf(vout[0][r]);
          bb[rowD * 72 + cc1] = f2bf(vout[1][r]);
        }
      }
    }
    __syncthreads();
    if (f32out) {
      float* y = (float*)yA;
#pragma unroll
      for (int it = 0; it < 2; ++it) {
        int r = it * 32 + trow, row = base + 64 * h + r;
        if (row < NVOX) {
          *(float4*)(y + (size_t)row * 64 + cp * 8) = *(const float4*)(fb4 + r * 68 + cp * 8);
          *(float4*)(y + (size_t)row * 64 + cp * 8 + 4) = *(const float4*)(fb4 + r * 68 + cp * 8 + 4);
        }
      }
    } else {
      u16* y = (u16*)(hB ? yB : yA);
#pragma unroll
      for (int it = 0; it < 2; ++it) {
        int r = it * 32 + trow, row = base + 64 * h + r;
        if (row < NVOX)
          *(uint4*)(y + (size_t)row * 64 + cp * 8) = *(const uint4*)(bb + r * 72 + cp * 8);
      }
    }
  }
  if (tid < 128) {
    int which = tid >> 6, c = tid & 63;
    float v = sred[0][which * 64 + c] + sred[1][which * 64 + c] +
              sred[2][which * 64 + c] + sred[3][which * 64 + c];
    atomicAdd(&st[(bid & (NREP - 1)) * 128 + which * 64 + c], v);
  }
}

// ---- round-6 serial conv (fallback tiers) ---------------------------------
template <bool IN_F32, bool FOLDED, int MODE>
__global__ __launch_bounds__(256, 4)
void conv_k(const void* __restrict__ fv, const int* __restrict__ nbr,
            const u16* __restrict__ wf, void* yv, float* __restrict__ st,
            float* io, const float* __restrict__ affD,
            const float* __restrict__ affB) {
  __shared__ __align__(16) float fb[128 * 68];
  __shared__ float sred[4][128];

  const int tid = threadIdx.x;
  const int wv = tid >> 6;
  const int lane = tid & 63;
  const int lrow = lane & 31;
  const int lq = lane >> 5;
  const int base = blockIdx.x * TM;
  const int gr = base + wv * 32 + lrow;

  int ids[9];
#pragma unroll
  for (int j = 0; j < 9; ++j) ids[j] = (gr < NVOX) ? nbr[gr * 9 + j] : NVOX;

  f32x16 acc0 = {0.f, 0.f, 0.f, 0.f, 0.f, 0.f, 0.f, 0.f,
                 0.f, 0.f, 0.f, 0.f, 0.f, 0.f, 0.f, 0.f};
  f32x16 acc1 = acc0;
  constexpr int KSTRIDE = FOLDED ? 5120 : 4096;

#pragma unroll
  for (int k = 0; k < 9; ++k) {
    if (k != 4) {
      if (__ballot(ids[k] < NVOX) == 0ull) continue;
    }
    const int id = ids[k];
    const bool ok = id < NVOX;
    uint4 af[4];
    if constexpr (IN_F32) {
      const float* p = (const float*)fv + (size_t)id * 64 + lq * 8;
#pragma unroll
      for (int ksi = 0; ksi < 4; ++ksi) {
        uint4 v0 = make_uint4(0u, 0u, 0u, 0u), v1 = v0;
        if (ok) { v0 = *(const uint4*)(p + ksi * 16); v1 = *(const uint4*)(p + ksi * 16 + 4); }
        af[ksi] = cvt8(v0, v1);
      }
    } else {
      const u16* p = (const u16*)fv + (size_t)id * 64 + lq * 8;
#pragma unroll
      for (int ksi = 0; ksi < 4; ++ksi) {
        uint4 v = make_uint4(0u, 0u, 0u, 0u);
        if (ok) v = *(const uint4*)(p + ksi * 16);
        af[ksi] = v;
      }
    }
    const u16* wb = wf + k * KSTRIDE;
#pragma unroll
    for (int ksi = 0; ksi < 4; ++ksi) {
      bf16x8 a = __builtin_bit_cast(bf16x8, af[ksi]);
      bf16x8 b0 = __builtin_bit_cast(bf16x8, *(const uint4*)(wb + (ksi * 2) * 512 + lane * 8));
      bf16x8 b1 = __builtin_bit_cast(bf16x8, *(const uint4*)(wb + (ksi * 2 + 1) * 512 + lane * 8));
      acc0 = __builtin_amdgcn_mfma_f32_32x32x16_bf16(a, b0, acc0, 0, 0, 0);
      acc1 = __builtin_amdgcn_mfma_f32_32x32x16_bf16(a, b1, acc1, 0, 0, 0);
    }
    if constexpr (FOLDED) {
      uint4 a4 = make_uint4(0u, 0u, 0u, 0u);
      if (lq == 0 && ok) ((u16*)&a4)[0] = 0x3F80u;
      bf16x8 a = __builtin_bit_cast(bf16x8, a4);
      bf16x8 b0 = __builtin_bit_cast(bf16x8, *(const uint4*)(wb + 8 * 512 + lane * 8));
      bf16x8 b1 = __builtin_bit_cast(bf16x8, *(const uint4*)(wb + 9 * 512 + lane * 8));
      acc0 = __builtin_amdgcn_mfma_f32_32x32x16_bf16(a, b0, acc0, 0, 0, 0);
      acc1 = __builtin_amdgcn_mfma_f32_32x32x16_bf16(a, b1, acc1, 0, 0, 0);
    }
  }

  const int cc0 = lrow, cc1 = 32 + lrow;
  float aD0 = 0.f, aD1 = 0.f, hD0 = 0.f, hD1 = 0.f;
  if constexpr (MODE == 2) {
    aD0 = affD[cc0]; hD0 = affD[64 + cc0];
    aD1 = affD[cc1]; hD1 = affD[64 + cc1];
  }
  float s0 = 0.f, q0 = 0.f, s1 = 0.f, q1 = 0.f;
  float vout[2][16];
#pragma unroll
  for (int r = 0; r < 16; ++r) {
    float v = acc0[r]; v = v > 0.f ? v : 0.01f * v;
    s0 += v; q0 += v * v; vout[0][r] = v;
    float w = acc1[r]; w = w > 0.f ? w : 0.01f * w;
    s1 += w; q1 += w * w; vout[1][r] = w;
  }
  if constexpr (MODE != 2) {
    s0 += __shfl_xor(s0, 32); q0 += __shfl_xor(q0, 32);
    s1 += __shfl_xor(s1, 32); q1 += __shfl_xor(q1, 32);
    if (lq == 0) {
      sred[wv][lrow] = s0; sred[wv][32 + lrow] = s1;
      sred[wv][64 + lrow] = q0; sred[wv][96 + lrow] = q1;
    }
  }
  if constexpr (MODE == 0) {
    u16* bb = (u16*)fb;
#pragma unroll
    for (int r = 0; r < 16; ++r) {
      int rowD = 32 * wv + (r & 3) + 8 * (r >> 2) + 4 * lq;
      bb[rowD * 72 + cc0] = f2bf(vout[0][r]);
      bb[rowD * 72 + cc1] = f2bf(vout[1][r]);
    }
  } else if constexpr (MODE == 2 || MODE == 3) {
#pragma unroll
    for (int r = 0; r < 16; ++r) {
      int rowD = 32 * wv + (r & 3) + 8 * (r >> 2) + 4 * lq;
      float v0 = vout[0][r], v1 = vout[1][r];
      if constexpr (MODE == 2) { v0 = fmaf(v0, aD0, hD0); v1 = fmaf(v1, aD1, hD1); }
      fb[rowD * 68 + cc0] = v0;
      fb[rowD * 68 + cc1] = v1;
    }
  }
  __syncthreads();

  const int trow = tid >> 3, cp = tid & 7;
  if constexpr (MODE == 0) {
    u16* y = (u16*)yv;
    const u16* bb = (const u16*)fb;
#pragma unroll
    for (int it = 0; it < 4; ++it) {
      int r = it * 32 + trow, row = base + r;
      if (row < NVOX)
        *(uint4*)(y + (size_t)row * 64 + cp * 8) = *(const uint4*)(bb + r * 72 + cp * 8);
    }
  }
  if constexpr (MODE == 3) {
    float* y = (float*)yv;
#pragma unroll
    for (int it = 0; it < 4; ++it) {
      int r = it * 32 + trow, row = base + r;
      if (row < NVOX) {
        *(float4*)(y + (size_t)row * 64 + cp * 8) = *(const float4*)(fb + r * 68 + cp * 8);
        *(float4*)(y + (size_t)row * 64 + cp * 8 + 4) = *(const float4*)(fb + r * 68 + cp * 8 + 4);
      }
    }
  }
  if constexpr (MODE == 2) {
    float* y = (float*)yv;
#pragma unroll
    for (int it = 0; it < 4; ++it) {
      int r = it * 32 + trow, row = base + r;
      if (row < NVOX) {
        float t[8], pp[8], o[8];
        *(float4*)&t[0] = *(const float4*)(fb + r * 68 + cp * 8);
        *(float4*)&t[4] = *(const float4*)(fb + r * 68 + cp * 8 + 4);
        *(float4*)&pp[0] = *(const float4*)(io + (size_t)row * 64 + cp * 8);
        *(float4*)&pp[4] = *(const float4*)(io + (size_t)row * 64 + cp * 8 + 4);
#pragma unroll
        for (int j = 0; j < 8; ++j) {
          int c = cp * 8 + j;
          o[j] = t[j] + fmaf(pp[j], affB[c], affB[64 + c]);
        }
        *(float4*)(y + (size_t)row * 64 + cp * 8) = *(const float4*)&o[0];
        *(float4*)(y + (size_t)row * 64 + cp * 8 + 4) = *(const float4*)&o[4];
      }
    }
  }
  if constexpr (MODE != 2) {
    if (tid < 128) {
      int which = tid >> 6, c = tid & 63;
      float v = sred[0][which * 64 + c] + sred[1][which * 64 + c] +
                sred[2][which * 64 + c] + sred[3][which * 64 + c];
      atomicAdd(&st[(blockIdx.x & (NREP - 1)) * 128 + which * 64 + c], v);
    }
  }
}

// prep: feat fp32 -> bf16, raw weight fragments (w1, w2), zero stats + zero row
__global__ void prep_all(const float* __restrict__ feat, const float* __restrict__ w1,
                         const float* __restrict__ w2, u16* __restrict__ wf,
                         u16* __restrict__ F, float* __restrict__ st,
                         u16* __restrict__ zr, int cvt_blocks) {
  const int bid = blockIdx.x, tid = threadIdx.x;
  if (bid < cvt_blocks) {
    int i8 = (bid * 256 + tid) * 8;
    if (i8 < NVOX * 64) {
      uint4 a = *(const uint4*)(feat + i8);
      uint4 b = *(const uint4*)(feat + i8 + 4);
      *(uint4*)(F + i8) = cvt8(a, b);
    }
    return;
  }
  int rb = bid - cvt_blocks;
  if (rb < 288) {   // raw frags: [slot 0|1][k][ks*2+ct][lane][j]
    int e = rb * 256 + tid;
    int slot = e / 36864, r = e % 36864;
    int k = r >> 12, rr = r & 4095;
    int frag = rr >> 9, lane = (rr >> 3) & 63, j = rr & 7;
    int ks = frag >> 1, ct = frag & 1;
    int cin = ks * 16 + (lane >> 5) * 8 + j;
    int cout = ct * 32 + (lane & 31);
    const float* src = slot ? w2 : w1;
    wf[e] = f2bf(src[k * 4096 + cin * 64 + cout]);
    return;
  }
  for (int i = tid; i < 4 * STG; i += 256) st[i] = 0.f;
  if (tid < 32) ((u32*)zr)[tid] = 0u;   // shared 128 B zero row (legacy, unused)
}

__device__ __forceinline__ void bn_from_replicas(const float* stp, const float* g,
                                                 const float* b, int c,
                                                 float* sc, float* sh) {
  float s = 0.f, q = 0.f;
#pragma unroll
  for (int r = 0; r < NREP; ++r) {
    s += stp[r * 128 + c];
    q += stp[r * 128 + 64 + c];
  }
  const float invn = 1.0f / (float)NVOX;
  float mean = s * invn;
  float var = q * invn - mean * mean;
  float sca = g[c] * rsqrtf(var + 1e-5f);
  *sc = sca;
  *sh = b[c] - mean * sca;
}

// fold both BN stages into both second-conv weights (one dispatch, 360 blocks)
__global__ void wscale2(const float* __restrict__ wA, float* __restrict__ stpA,
                        const float* __restrict__ gA, const float* __restrict__ bA,
                        u16* __restrict__ dA,
                        const float* __restrict__ wB, float* __restrict__ stpB,
                        const float* __restrict__ gB, const float* __restrict__ bB,
                        u16* __restrict__ dB) {
  __shared__ float sc[64], sh[64];
  const int tid = threadIdx.x;
  const bool hB = (blockIdx.x >= 180);
  const float* wraw = hB ? wB : wA;
  float* stp = hB ? stpB : stpA;
  const float* g = hB ? gB : gA;
  const float* b = hB ? bB : bA;
  u16* dst = hB ? dB : dA;
  const int blk = hB ? blockIdx.x - 180 : blockIdx.x;
  if (tid < 64) {
    float a, h;
    bn_from_replicas(stp, g, b, tid, &a, &h);
    sc[tid] = a; sh[tid] = h;
    if (blk == 0) { stp[NREP * 128 + tid] = a; stp[NREP * 128 + 64 + tid] = h; }
  }
  __syncthreads();
  int e = blk * 256 + tid;   // [0, 46080)
  int k = e / 5120, r = e % 5120;
  int frag = r >> 9, lane = (r >> 3) & 63, j = r & 7;
  int ks = frag >> 1, ct = frag & 1;
  int cout = ct * 32 + (lane & 31);
  u16 val = 0;
  if (ks < 4) {
    int cin = ks * 16 + (lane >> 5) * 8 + j;
    val = f2bf(sc[cin] * wraw[k * 4096 + cin * 64 + cout]);
  } else if (((lane >> 5) == 0) && j == 0) {
    float acc = 0.f;
    for (int c = 0; c < 64; ++c) acc += sh[c] * wraw[k * 4096 + c * 64 + cout];
    val = f2bf(acc);
  }
  dst[e] = val;
}

// both output-BN affines in one tiny dispatch (fallback tiers)
__global__ void finalize2(float* __restrict__ stA, const float* __restrict__ gA,
                          const float* __restrict__ bA, float* __restrict__ stB,
                          const float* __restrict__ gB, const float* __restrict__ bB) {
  int t = threadIdx.x;
  float* stp = (t < 64) ? stA : stB;
  const float* g = (t < 64) ? gA : gB;
  const float* b = (t < 64) ? bA : bB;
  int c = t & 63;
  if (t < 128) {
    float a, h;
    bn_from_replicas(stp, g, b, c, &a, &h);
    stp[NREP * 128 + c] = a;
    stp[NREP * 128 + 64 + c] = h;
  }
}

// io (fp32, in place) = affB(io) + affD(y3 bf16)   (fallback tiers)
__global__ void final_add(const u16* __restrict__ y3, float* io,
                          const float* __restrict__ affB, const float* __restrict__ affD) {
  int i8 = (blockIdx.x * 256 + threadIdx.x) * 8;
  if (i8 < NVOX * 64) {
    float a[8];
    *(float4*)&a[0] = *(const float4*)(io + i8);
    *(float4*)&a[4] = *(const float4*)(io + i8 + 4);
    uint4 vd = *(const uint4*)(y3 + i8);
    const u16* pd = (const u16*)&vd;
    int cb = i8 & 63;
    float o[8];
#pragma unroll
    for (int j = 0; j < 8; ++j) {
      int c = cb + j;
      o[j] = fmaf(a[j], affB[c], affB[64 + c]) + fmaf(bf2f(pd[j]), affD[c], affD[64 + c]);
    }
    *(float4*)(io + i8) = *(const float4*)&o[0];
    *(float4*)(io + i8 + 4) = *(const float4*)&o[4];
  }
}

// fused tier: finalize2 + final_add merged (affines computed per-block in LDS)
__global__ void final_add2(const u16* __restrict__ y3, float* io,
                           float* __restrict__ stB, const float* __restrict__ gB,
                           const float* __restrict__ bB,
                           float* __restrict__ stD, const float* __restrict__ gD,
                           const float* __restrict__ bD) {
  __shared__ float aff[4][64];   // [B scale][B shift][D scale][D shift]
  const int t = threadIdx.x;
  if (t < 128) {
    float a, h;
    if (t < 64) { bn_from_replicas(stB, gB, bB, t, &a, &h); aff[0][t] = a; aff[1][t] = h; }
    else { int c = t - 64; bn_from_replicas(stD, gD, bD, c, &a, &h); aff[2][c] = a; aff[3][c] = h; }
  }
  __syncthreads();
  int i8 = (blockIdx.x * 256 + t) * 8;
  if (i8 < NVOX * 64) {
    float a[8];
    *(float4*)&a[0] = *(const float4*)(io + i8);
    *(float4*)&a[4] = *(const float4*)(io + i8 + 4);
    uint4 vd = *(const uint4*)(y3 + i8);
    const u16* pd = (const u16*)&vd;
    int cb = i8 & 63;
    float o[8];
#pragma unroll
    for (int j = 0; j < 8; ++j) {
      int c = cb + j;
      o[j] = fmaf(a[j], aff[0][c], aff[1][c]) + fmaf(bf2f(pd[j]), aff[2][c], aff[3][c]);
    }
    *(float4*)(io + i8) = *(const float4*)&o[0];
    *(float4*)(io + i8 + 4) = *(const float4*)&o[4];
  }
}

extern "C" void kernel_launch(void* const* d_in, const int* in_sizes, int n_in,
                              void* d_out, int out_size, void* d_ws, size_t ws_size,
                              hipStream_t stream) {
  const float* feat = (const float*)d_in[0];
  const float* w1 = (const float*)d_in[1];
  const float* w1_2 = (const float*)d_in[2];
  const float* w2 = (const float*)d_in[3];
  const float* w3 = (const float*)d_in[4];
  const float* g0 = (const float*)d_in[5];
  const float* b0 = (const float*)d_in[6];
  const float* g0_2 = (const float*)d_in[7];
  const float* b0_2 = (const float*)d_in[8];
  const float* g1 = (const float*)d_in[9];
  const float* b1 = (const float*)d_in[10];
  const float* g2 = (const float*)d_in[11];
  const float* b2 = (const float*)d_in[12];
  const int* nbr13 = (const int*)d_in[13];
  const int* nbr31 = (const int*)d_in[14];
  float* out = (float*)d_out;

  char* ws = (char*)d_ws;
  float* st = (float*)ws;                         // 4 stages x 4224 f = 67,584 B
  u16* wf = (u16*)(ws + 67584);                   // 331,776 B of fragments
  u16* s0 = wf;                                   // w1 raw      (36,864 u16)
  u16* s1 = wf + 36864;                           // w2 raw
  u16* s2 = wf + 73728;                           // w1_2 folded (46,080 u16)
  u16* s3 = wf + 119808;                          // w3 folded
  u16* zr = (u16*)(ws + 399360);                  // legacy zero row, 128 B
  u16* F = (u16*)(ws + 399488);                   // feat bf16 (later Y3), 25.6 MB
  u16* A1 = F + (size_t)NVOX * 64;                // 25.6 MB
  u16* A2 = A1 + (size_t)NVOX * 64;               // 25.6 MB (fused plan only)
  const size_t base_sz = 399488;
  const size_t need_fused = base_sz + 3ull * NVOX * 64 * 2;
  const size_t need_serial = base_sz + 2ull * NVOX * 64 * 2;

  float* st0 = st, *st1 = st + STG, *st2 = st + 2 * STG, *st3 = st + 3 * STG;

  if (ws_size >= need_fused) {
    prep_all<<<6539, 256, 0, stream>>>(feat, w1, w2, wf, F, st, zr, 6250);
    // convA: conv1(F,nbr13,s0)->A1,st0  ||  conv2(F,nbr31,s1)->A2,st2
    conv_fused<0><<<2 * NBLK, 256, 0, stream>>>(F, F, nbr13, nbr31, s0, s1,
                                                A1, A2, st0, st2);
    wscale2<<<360, 256, 0, stream>>>(w1_2, st0, g0, b0, s2, w3, st2, g1, b1, s3);
    // convB: conv1_2(A1,nbr31,s2)->out fp32,st1  ||  conv3(A2,nbr13,s3)->F bf16,st3
    conv_fused<1><<<2 * NBLK, 256, 0, stream>>>(A1, A2, nbr31, nbr13, s2, s3,
                                                out, F, st1, st3);
    final_add2<<<6250, 256, 0, stream>>>(F, out, st1, g0_2, b0_2, st3, g2, b2);
  } else if (ws_size >= need_serial) {
    prep_all<<<6539, 256, 0, stream>>>(feat, w1, w2, wf, F, st, zr, 6250);
    conv_k<false, false, 0><<<NBLK, 256, 0, stream>>>(F, nbr13, s0, A1, st0, nullptr, nullptr, nullptr);
    wscale2<<<180, 256, 0, stream>>>(w1_2, st0, g0, b0, s2, w3, st2, g1, b1, s3);  // only half used
    conv_k<false, true, 3><<<NBLK, 256, 0, stream>>>(A1, nbr31, s2, out, st1, nullptr, nullptr, nullptr);
    conv_k<false, false, 0><<<NBLK, 256, 0, stream>>>(F, nbr31, s1, A1, st2, nullptr, nullptr, nullptr);
    wscale2<<<360, 256, 0, stream>>>(w1_2, st0, g0, b0, s2, w3, st2, g1, b1, s3);
    conv_k<false, true, 0><<<NBLK, 256, 0, stream>>>(A1, nbr13, s3, F, st3, nullptr, nullptr, nullptr);
    finalize2<<<1, 128, 0, stream>>>(st1, g0_2, b0_2, st3, g2, b2);
    final_add<<<6250, 256, 0, stream>>>(F, out, st1 + NREP * 128, st3 + NREP * 128);
  } else {
    // minimal-ws: recompute path (round-6 small)
    u16* Az = F;
    prep_all<<<289, 256, 0, stream>>>(feat, w1, w2, wf, nullptr, st, zr, 0);
    conv_k<true, false, 0><<<NBLK, 256, 0, stream>>>(feat, nbr13, s0, Az, st0, nullptr, nullptr, nullptr);
    wscale2<<<180, 256, 0, stream>>>(w1_2, st0, g0, b0, s2, w3, st2, g1, b1, s3);
    conv_k<false, true, 3><<<NBLK, 256, 0, stream>>>(Az, nbr31, s2, out, st1, nullptr, nullptr, nullptr);
    finalize2<<<1, 128, 0, stream>>>(st1, g0_2, b0_2, st3, g2, b2);
    conv_k<true, false, 0><<<NBLK, 256, 0, stream>>>(feat, nbr31, s1, Az, st2, nullptr, nullptr, nullptr);
    wscale2<<<360, 256, 0, stream>>>(w1_2, st0, g0, b0, s2, w3, st2, g1, b1, s3);
    conv_k<false, true, 1><<<NBLK, 256, 0, stream>>>(Az, nbr13, s3, nullptr, st3, nullptr, nullptr, nullptr);
    finalize2<<<1, 128, 0, stream>>>(st1, g0_2, b0_2, st3, g2, b2);
    conv_k<false, true, 2><<<NBLK, 256, 0, stream>>>(Az, nbr13, s3, out, nullptr, out,
                                                     st3 + NREP * 128, st1 + NREP * 128);
  }
}